// Round 1
// baseline (180.368 us; speedup 1.0000x reference)
//
#include <hip/hip_runtime.h>

typedef __attribute__((ext_vector_type(8))) short short8;
typedef __attribute__((ext_vector_type(4))) float f32x4;

__device__ __forceinline__ unsigned short f2bf(float f) {
    union { float f; unsigned int i; } v; v.f = f;
    unsigned int x = v.i;
    return (unsigned short)((x + 0x7FFFu + ((x >> 16) & 1u)) >> 16); // RNE, finite inputs
}
__device__ __forceinline__ f32x4 mfma16(short8 a, short8 b, f32x4 c) {
    return __builtin_amdgcn_mfma_f32_16x16x32_bf16(a, b, c, 0, 0, 0);
}

// ---------------------------------------------------------------------------
// K1: fused input prep, fully-coalesced loads (1 KB contiguous per wave instr).
// Blocks 0..4095: per (b,c) plane of fp32 x. Thread t loads float4s at
// {t, t+256, t+512, t+768}; partial quad-sums regrouped via LDS:
// part2[256j+t] = sum of pixels 4t+1024j..+3  ==  part2[16h+c4] = quad (h,c4).
//   xsum[g]  = part2[16(g>>2)+4(g&3) .. +3]        (16 consecutive pixels)
//   xavg[n]  = mean of part2[(4bh+i)*16+bw], i=0..3 (4x4 spatial block)
// Blocks 4096..4479: Wq|Wk|Wv fp32->bf16 (coalesced float4 pairs f, f+256).
// ---------------------------------------------------------------------------
__global__ void prep_kernel(const float* __restrict__ x,
                            const float* __restrict__ Wq,
                            const float* __restrict__ Wk,
                            const float* __restrict__ Wv,
                            unsigned short* __restrict__ xavg,
                            unsigned short* __restrict__ xsum,
                            unsigned short* __restrict__ Wb)
{
    const int blk = blockIdx.x;
    const int t = threadIdx.x;
    if (blk >= 4096) {                      // weight conversion
        const int f = (blk - 4096) * 512 + t;   // float4 id; pair (f, f+256)
        const int m = f >> 16;                  // 65536 float4 per matrix
        const int o = f & 65535;
        const float4* s4 = (const float4*)((m == 0) ? Wq : (m == 1) ? Wk : Wv);
        float4 a = s4[o];
        float4 b = s4[o + 256];
        ushort4* d4 = (ushort4*)(Wb + (size_t)m * 262144);
        d4[o]       = make_ushort4(f2bf(a.x), f2bf(a.y), f2bf(a.z), f2bf(a.w));
        d4[o + 256] = make_ushort4(f2bf(b.x), f2bf(b.y), f2bf(b.z), f2bf(b.w));
        return;
    }
    const int b = blk >> 9;                 // plane = b*512 + c
    const int c = blk & 511;

    const float4* x4 = (const float4*)(x + (size_t)blk * 4096);
    float4 f0 = x4[t], f1 = x4[t + 256], f2 = x4[t + 512], f3 = x4[t + 768];

    __shared__ float part2[1024];
    part2[t]       = f0.x + f0.y + f0.z + f0.w;
    part2[t + 256] = f1.x + f1.y + f1.z + f1.w;
    part2[t + 512] = f2.x + f2.y + f2.z + f2.w;
    part2[t + 768] = f3.x + f3.y + f3.z + f3.w;
    __syncthreads();

    // xsum: group g = t (16 consecutive flat pixels)
    {
        const int base = 16 * (t >> 2) + 4 * (t & 3);
        float4 q = *(const float4*)&part2[base];
        xsum[((size_t)b * 256 + t) * 512 + c] = f2bf(q.x + q.y + q.z + q.w);
    }
    // xavg: spatial block n = t = bh*16+bw
    {
        const int bh = t >> 4, bw = t & 15;
        float m = (part2[(bh * 4 + 0) * 16 + bw] + part2[(bh * 4 + 1) * 16 + bw] +
                   part2[(bh * 4 + 2) * 16 + bw] + part2[(bh * 4 + 3) * 16 + bw]) * 0.0625f;
        xavg[((size_t)b * 256 + t) * 512 + c] = f2bf(m);
    }
}

// ---------------------------------------------------------------------------
// K2: joint projection (384 blocks). 32x64 tile/wave, 6 loads -> 8 MFMAs.
// Blocks 0..255:  QK[2048x1024] = xavg @ [Wq;Wk]^T + [bq;bk].
// Blocks 256..383: VsT[b][c][m] = (xsum[b] @ Wv^T + 16*bv)^T.
// ---------------------------------------------------------------------------
__global__ void __launch_bounds__(256, 2)
proj_gemm(const unsigned short* __restrict__ xavg,
          const unsigned short* __restrict__ xsum,
          const unsigned short* __restrict__ Wb,
          const float* __restrict__ bq,
          const float* __restrict__ bk,
          const float* __restrict__ bv,
          unsigned short* __restrict__ QK,
          unsigned short* __restrict__ VsT)
{
    const int blk = blockIdx.x;
    const int lane = threadIdx.x & 63, quad = lane >> 4, r16 = lane & 15;
    const int w = threadIdx.x >> 6;

    if (blk < 256) {                        // ---- QK projection ----
        const int wave = blk * 4 + w;       // 0..1023
        const int mt2 = wave >> 4;          // 0..63 (32-row tiles)
        const int nt4 = wave & 15;          // 0..15 (64-col tiles)
        const unsigned short* xp0 = xavg + (size_t)(mt2 * 32 + r16) * 512 + quad * 8;
        const unsigned short* xp1 = xp0 + 16 * 512;
        const unsigned short* wp0 = Wb + (size_t)(nt4 * 64 + r16) * 512 + quad * 8;
        const unsigned short* wp1 = wp0 + 16 * 512;
        const unsigned short* wp2 = wp0 + 32 * 512;
        const unsigned short* wp3 = wp0 + 48 * 512;

        f32x4 a00 = {0,0,0,0}, a01 = a00, a02 = a00, a03 = a00;
        f32x4 a10 = a00, a11 = a00, a12 = a00, a13 = a00;
#pragma unroll 4
        for (int k = 0; k < 512; k += 32) {
            short8 qa0 = *(const short8*)(xp0 + k);
            short8 qa1 = *(const short8*)(xp1 + k);
            short8 b0 = *(const short8*)(wp0 + k);
            short8 b1 = *(const short8*)(wp1 + k);
            short8 b2 = *(const short8*)(wp2 + k);
            short8 b3 = *(const short8*)(wp3 + k);
            a00 = mfma16(qa0, b0, a00); a01 = mfma16(qa0, b1, a01);
            a02 = mfma16(qa0, b2, a02); a03 = mfma16(qa0, b3, a03);
            a10 = mfma16(qa1, b0, a10); a11 = mfma16(qa1, b1, a11);
            a12 = mfma16(qa1, b2, a12); a13 = mfma16(qa1, b3, a13);
        }
        const int row0 = mt2 * 32 + quad * 4;
        f32x4 accs0[4] = {a00, a01, a02, a03};
        f32x4 accs1[4] = {a10, a11, a12, a13};
#pragma unroll
        for (int j = 0; j < 4; ++j) {
            const int c = nt4 * 64 + j * 16 + r16;
            const float bias = (c < 512) ? bq[c] : bk[c - 512];
#pragma unroll
            for (int r = 0; r < 4; ++r) {
                QK[(size_t)(row0 + r) * 1024 + c]      = f2bf(accs0[j][r] + bias);
                QK[(size_t)(row0 + 16 + r) * 1024 + c] = f2bf(accs1[j][r] + bias);
            }
        }
    } else {                                // ---- V projection (transposed) ----
        const int vblk = blk - 256;         // 0..127
        const int b = vblk >> 4;            // 0..7
        const int wave = (vblk & 15) * 4 + w;   // 0..63
        const int mt2 = wave >> 3;          // 0..7
        const int nt4 = wave & 7;           // 0..7
        const unsigned short* xp0 = xsum + (size_t)b * 131072 + (size_t)(mt2 * 32 + r16) * 512 + quad * 8;
        const unsigned short* xp1 = xp0 + 16 * 512;
        const unsigned short* wp0 = Wb + 524288 + (size_t)(nt4 * 64 + r16) * 512 + quad * 8;
        const unsigned short* wp1 = wp0 + 16 * 512;
        const unsigned short* wp2 = wp0 + 32 * 512;
        const unsigned short* wp3 = wp0 + 48 * 512;

        f32x4 a00 = {0,0,0,0}, a01 = a00, a02 = a00, a03 = a00;
        f32x4 a10 = a00, a11 = a00, a12 = a00, a13 = a00;
#pragma unroll 4
        for (int k = 0; k < 512; k += 32) {
            short8 qa0 = *(const short8*)(xp0 + k);
            short8 qa1 = *(const short8*)(xp1 + k);
            short8 b0 = *(const short8*)(wp0 + k);
            short8 b1 = *(const short8*)(wp1 + k);
            short8 b2 = *(const short8*)(wp2 + k);
            short8 b3 = *(const short8*)(wp3 + k);
            a00 = mfma16(qa0, b0, a00); a01 = mfma16(qa0, b1, a01);
            a02 = mfma16(qa0, b2, a02); a03 = mfma16(qa0, b3, a03);
            a10 = mfma16(qa1, b0, a10); a11 = mfma16(qa1, b1, a11);
            a12 = mfma16(qa1, b2, a12); a13 = mfma16(qa1, b3, a13);
        }
        unsigned short* vb = VsT + (size_t)b * 131072;
        const int m0 = mt2 * 32 + quad * 4;
        f32x4 accs0[4] = {a00, a01, a02, a03};
        f32x4 accs1[4] = {a10, a11, a12, a13};
#pragma unroll
        for (int j = 0; j < 4; ++j) {
            const int c = nt4 * 64 + j * 16 + r16;
            const float bias = 16.f * bv[c];
#pragma unroll
            for (int r = 0; r < 4; ++r) {
                vb[(size_t)c * 256 + m0 + r]      = f2bf(accs0[j][r] + bias);
                vb[(size_t)c * 256 + m0 + 16 + r] = f2bf(accs1[j][r] + bias);
            }
        }
    }
}

// ---------------------------------------------------------------------------
// K3: scores + softmax, 16-row strips (128 blocks: 16 strips x 8 batches).
// 4 waves: each computes 16 rows x 64 cols (K=512, 5 loads -> 4 MFMAs) into
// LDS S; softmax with 16 threads/row -> bf16 Amat (coalesced 512 B rows).
// ---------------------------------------------------------------------------
__global__ void __launch_bounds__(256, 2)
score_softmax(const unsigned short* __restrict__ QK,
              unsigned short* __restrict__ Amat)
{
    __shared__ float S[16][257];
    const int b = blockIdx.y, strip = blockIdx.x;   // strip: 0..15
    const int w = threadIdx.x >> 6, lane = threadIdx.x & 63;
    const int quad = lane >> 4, r16 = lane & 15;

    {
        const unsigned short* qp = QK + (size_t)(b * 256 + strip * 16 + r16) * 1024 + quad * 8;
        const unsigned short* kp0 = QK + (size_t)(b * 256 + w * 64 + r16) * 1024 + 512 + quad * 8;
        const unsigned short* kp1 = kp0 + 16 * 1024;
        const unsigned short* kp2 = kp0 + 32 * 1024;
        const unsigned short* kp3 = kp0 + 48 * 1024;

        f32x4 a0 = {0,0,0,0}, a1 = a0, a2 = a0, a3 = a0;
#pragma unroll 4
        for (int k = 0; k < 512; k += 32) {
            short8 qa = *(const short8*)(qp + k);
            short8 b0 = *(const short8*)(kp0 + k);
            short8 b1 = *(const short8*)(kp1 + k);
            short8 b2 = *(const short8*)(kp2 + k);
            short8 b3 = *(const short8*)(kp3 + k);
            a0 = mfma16(qa, b0, a0); a1 = mfma16(qa, b1, a1);
            a2 = mfma16(qa, b2, a2); a3 = mfma16(qa, b3, a3);
        }
        f32x4 accs[4] = {a0, a1, a2, a3};
#pragma unroll
        for (int j = 0; j < 4; ++j) {
            const int col = w * 64 + j * 16 + r16;
#pragma unroll
            for (int r = 0; r < 4; ++r)
                S[quad * 4 + r][col] = accs[j][r];
        }
    }
    __syncthreads();

    {
        const int t = threadIdx.x;
        const int r = t >> 4, idx = t & 15;     // row r, cols idx*16..+15
        float v[16];
        float mx = -3.4e38f;
#pragma unroll
        for (int j = 0; j < 16; ++j) {
            v[j] = S[r][idx * 16 + j] * 0.044194173824159216f;
            mx = fmaxf(mx, v[j]);
        }
        mx = fmaxf(mx, __shfl_xor(mx, 1));
        mx = fmaxf(mx, __shfl_xor(mx, 2));
        mx = fmaxf(mx, __shfl_xor(mx, 4));
        mx = fmaxf(mx, __shfl_xor(mx, 8));
        float sum = 0.f;
#pragma unroll
        for (int j = 0; j < 16; ++j) { v[j] = __expf(v[j] - mx); sum += v[j]; }
        sum += __shfl_xor(sum, 1);
        sum += __shfl_xor(sum, 2);
        sum += __shfl_xor(sum, 4);
        sum += __shfl_xor(sum, 8);
        const float inv = 1.f / sum;
        unsigned short* ap = Amat + (size_t)b * 65536 + (size_t)(strip * 16 + r) * 256 + idx * 16;
#pragma unroll
        for (int j = 0; j < 16; j += 4)
            *(ushort4*)(ap + j) = make_ushort4(f2bf(v[j] * inv), f2bf(v[j + 1] * inv),
                                               f2bf(v[j + 2] * inv), f2bf(v[j + 3] * inv));
    }
}

// ---------------------------------------------------------------------------
// K4: out = expand16(A @ Vsum). Grid (16 half-strips x 8 c-eighths, 8 b) =
// 1024 blocks, 4 blocks/CU (LDS 4.4 KB), 16 waves/CU. One 16x16 tile/wave,
// K=256 fully unrolled, frags direct from global. Transpose via tiny LDS,
// then fully-coalesced 64 MiB write (1 KB contiguous per wave instruction).
// ---------------------------------------------------------------------------
__global__ void __launch_bounds__(256, 4)
av_expand(const unsigned short* __restrict__ Amat,
          const unsigned short* __restrict__ VsT,
          float* __restrict__ out)
{
    __shared__ float osT[64][17];           // [local ch][local n]
    const int b = blockIdx.y;
    const int sh = blockIdx.x >> 3;         // 0..15: 16-row half-strip
    const int cq = blockIdx.x & 7;          // 0..7: 64-channel group
    const int w = threadIdx.x >> 6, lane = threadIdx.x & 63;
    const int quad = lane >> 4, r16 = lane & 15;

    {
        const unsigned short* ap = Amat + (size_t)b * 65536 + (size_t)(sh * 16 + r16) * 256 + quad * 8;
        const unsigned short* vp = VsT + (size_t)b * 131072 +
                                   (size_t)(cq * 64 + w * 16 + r16) * 256 + quad * 8;
        f32x4 acc = {0.f, 0.f, 0.f, 0.f};
#pragma unroll
        for (int k = 0; k < 256; k += 32) {
            short8 a0 = *(const short8*)(ap + k);
            short8 b0 = *(const short8*)(vp + k);
            acc = mfma16(a0, b0, acc);
        }
#pragma unroll
        for (int r = 0; r < 4; ++r)
            osT[w * 16 + r16][quad * 4 + r] = acc[r];
    }
    __syncthreads();

    {
        const int t = threadIdx.x;
        const int ch4 = t >> 6;             // wave index: ch = it*4 + ch4
        const int j = t & 63;               // float4 index within channel
        const int n = j >> 2;               // local block-row 0..15
        float* obase = out + (size_t)(b * 512 + cq * 64) * 4096 + sh * 256 + j * 4;
#pragma unroll
        for (int it = 0; it < 16; ++it) {
            const int ch = it * 4 + ch4;
            const float v = osT[ch][n];
            *(float4*)(obase + (size_t)ch * 4096) = make_float4(v, v, v, v);
        }
    }
}

extern "C" void kernel_launch(void* const* d_in, const int* in_sizes, int n_in,
                              void* d_out, int out_size, void* d_ws, size_t ws_size,
                              hipStream_t stream) {
    const float* x  = (const float*)d_in[0];
    const float* Wq = (const float*)d_in[1];
    const float* bq = (const float*)d_in[2];
    const float* Wk = (const float*)d_in[3];
    const float* bk = (const float*)d_in[4];
    const float* Wv = (const float*)d_in[5];
    const float* bv = (const float*)d_in[6];
    float* out = (float*)d_out;

    // All scratch in d_ws (13 MB); fully written before read each call.
    // d_out written exactly once (by av_expand).
    unsigned short* Wb   = (unsigned short*)d_ws;    // 786432 shorts (Wq|Wk|Wv)
    unsigned short* xavg = Wb + 786432;              // 1048576
    unsigned short* xsum = xavg + 1048576;           // 1048576
    unsigned short* QK   = xsum + 1048576;           // 2097152 (2048x1024)
    unsigned short* VsT  = QK + 2097152;             // 1048576 (8 x 512x256)
    unsigned short* Amat = VsT + 1048576;            // 524288  (8 x 256x256)

    // K1: plane reductions (4096 blocks) + weight convert (384 blocks)
    prep_kernel<<<4480, 256, 0, stream>>>(x, Wq, Wk, Wv, xavg, xsum, Wb);
    // K2: QK = xavg @ [Wq;Wk]^T + bias  AND  VsT = (xsum @ Wv^T + 16*bv)^T
    proj_gemm<<<384, 256, 0, stream>>>(xavg, xsum, Wb, bq, bk, bv, QK, VsT);
    // K3: A = softmax(QK^T/sqrt(512)) once per 16-row strip -> Amat (d_ws)
    score_softmax<<<dim3(16, 8), 256, 0, stream>>>(QK, Amat);
    // K4: out = expand16(A @ Vsum), write-bound, high occupancy
    av_expand<<<dim3(128, 8), 256, 0, stream>>>(Amat, VsT, out);
}